// Round 12
// baseline (144.191 us; speedup 1.0000x reference)
//
#include <hip/hip_runtime.h>
#include <hip/hip_bf16.h>

typedef unsigned short u16;
typedef unsigned int u32;
typedef short v8s __attribute__((ext_vector_type(8)));
typedef float v4f __attribute__((ext_vector_type(4)));

__device__ __forceinline__ float bflo(u32 d){union{u32 i;float f;}u;u.i=d<<16;return u.f;}
__device__ __forceinline__ float bfhi(u32 d){union{u32 i;float f;}u;u.i=d&0xffff0000u;return u.f;}
// Packed f32x2 -> bf16x2; compiler emits v_cvt_pk_bf16_f32 from this (m240).
__device__ __forceinline__ u32 cvtpk(float a, float b){
    __hip_bfloat162 h = __float22bfloat162_rn(make_float2(a, b));
    u32 r; __builtin_memcpy(&r, &h, sizeof(r)); return r;
}
__device__ __forceinline__ v8s pack8(const float* w){
    union { uint4 u; v8s v; } c;
    c.u.x = cvtpk(w[0],w[1]); c.u.y = cvtpk(w[2],w[3]);
    c.u.z = cvtpk(w[4],w[5]); c.u.w = cvtpk(w[6],w[7]);
    return c.v;
}

// Transposed flash for TWO batch elements (ILP-2). ADJ row r0 comes from
// REGISTERS (adjr[8], preloaded at kernel entry) -> zero global loads here.
// expb layout (floats): s*512 + {0:Ei,128:Fi,256:Ej,384:Fj} + row.
// whtb: element s at +s*9216 u16, [col][136] bf16.
// acc[s][ct][reg] = O_s[r0][16ct+4q4+reg]; accD[s][*] = D_s[r0].
__device__ __forceinline__ void flash_att2(
    int wv, int l15, int q4,
    const float4 adjr[8],
    const float* __restrict__ expb,
    const u16* __restrict__ whtb,
    v4f acc[2][4], v4f accD[2])
{
    const int r0 = 16*wv + l15;
    const float Ei0 = expb[r0],       Fi0 = expb[128 + r0];
    const float Ei1 = expb[512 + r0], Fi1 = expb[640 + r0];
    const v8s ONES = {16256,16256,16256,16256,16256,16256,16256,16256}; // bf16 1.0
    #pragma unroll
    for (int s = 0; s < 2; ++s) {
        accD[s] = (v4f){0.f,0.f,0.f,0.f};
        #pragma unroll
        for (int ct = 0; ct < 4; ++ct) acc[s][ct] = (v4f){0.f,0.f,0.f,0.f};
    }

    #pragma unroll
    for (int ks = 0; ks < 4; ++ks) {
        const int ko = ks*32 + q4*8;
        float w0[8], w1[8];
        #pragma unroll
        for (int half = 0; half < 2; ++half) {
            float4 E0 = *(const float4*)(expb + 256 + ko + 4*half);
            float4 F0 = *(const float4*)(expb + 384 + ko + 4*half);
            float4 E1 = *(const float4*)(expb + 768 + ko + 4*half);
            float4 F1 = *(const float4*)(expb + 896 + ko + 4*half);
            const float4 a = adjr[2*ks + half];                 // registers
            float Ev0[4] = {E0.x,E0.y,E0.z,E0.w};
            float Fv0[4] = {F0.x,F0.y,F0.z,F0.w};
            float Ev1[4] = {E1.x,E1.y,E1.z,E1.w};
            float Fv1[4] = {F1.x,F1.y,F1.z,F1.w};
            float av[4]  = {a.x,a.y,a.z,a.w};
            #pragma unroll
            for (int k = 0; k < 4; ++k) {
                w0[half*4 + k] = fmaxf(Ei0*Ev0[k], Fi0*Fv0[k]) * av[k];
                w1[half*4 + k] = fmaxf(Ei1*Ev1[k], Fi1*Fv1[k]) * av[k];
            }
        }
        v8s A0 = pack8(w0), A1 = pack8(w1);
        accD[0] = __builtin_amdgcn_mfma_f32_16x16x32_bf16(ONES, A0, accD[0], 0,0,0);
        accD[1] = __builtin_amdgcn_mfma_f32_16x16x32_bf16(ONES, A1, accD[1], 0,0,0);
        #pragma unroll
        for (int ct = 0; ct < 4; ++ct) {
            v8s Wt0 = *(const v8s*)(whtb + (16*ct + l15)*136 + ko);
            v8s Wt1 = *(const v8s*)(whtb + 9216 + (16*ct + l15)*136 + ko);
            acc[0][ct] = __builtin_amdgcn_mfma_f32_16x16x32_bf16(Wt0, A0, acc[0][ct], 0,0,0);
            acc[1][ct] = __builtin_amdgcn_mfma_f32_16x16x32_bf16(Wt1, A1, acc[1][ct], 0,0,0);
        }
    }
}

// 512 threads (8 waves), TWO batch elements per block (grid 512 = 2 blocks/CU,
// all blocks resident -> kernel time == one block's critical path).
// r10: h1 register-only (P6 A-frags via q4-group shuffles), 5 barriers.
// r11: W2 pre-packed into LDS fragment layout (P0 wave 3).
// r12: ADJ row r0 preloaded into 8xfloat4 REGISTERS at kernel entry; loads
// retire under P0/P1, so both flash phases run with zero global loads and
// no cold-miss latency (harness poisons L2/L3 right before launch).
// launch_bounds (512,4): cap 128 VGPR; ",7" proved to force spills (r5/r7).
__global__ __launch_bounds__(512, 4) void graphmixer_kernel(
    const float* __restrict__ C,     // (1024,128)
    const float* __restrict__ ADJ,   // (128,128)
    const float* __restrict__ EMB,   // (128,8)
    const float* __restrict__ W1,    // (9,64)
    const float* __restrict__ A1,    // (128)
    const float* __restrict__ W2,    // (64,64)
    const float* __restrict__ A2,    // (128)
    const float* __restrict__ LN1G, const float* __restrict__ LN1B,
    const float* __restrict__ LN2G, const float* __restrict__ LN2B,
    const float* __restrict__ HGW,  const float* __restrict__ HGB,
    const float* __restrict__ MLP1W, const float* __restrict__ MLP1B,
    const float* __restrict__ MLP2W, const float* __restrict__ MLP2B,
    const float* __restrict__ HMW,  const float* __restrict__ HMB,
    const float* __restrict__ G1W,  const float* __restrict__ G1B,
    const float* __restrict__ G2W,  const float* __restrict__ G2B,
    float* __restrict__ OUT)
{
    const int blk = blockIdx.x, t = threadIdx.x;
    const int lane = t & 63, wv = t >> 6;   // wv 0..7
    const int l15 = lane & 15, q4 = lane >> 4;

    // ---- r12: issue ADJ row loads FIRST; they complete under P0/P1 ----
    const int r0g = 16*wv + l15;
    const float4* arow = (const float4*)(ADJ + r0g*128) + q4*2;
    float4 adjr[8];
    #pragma unroll
    for (int ks = 0; ks < 4; ++ks) {
        adjr[2*ks]   = arow[ks*8];
        adjr[2*ks+1] = arow[ks*8 + 1];
    }

    __shared__ __align__(16) unsigned char smem[56128];
    // R1_s: [64][136] bf16 Wh1T then Wh2T (time-muxed across b3).
    u16*   R1   = (u16*)(smem);                    // +s*18432 bytes (9216 u16)
    float* expb = (float*)(smem + 36864);          // 2 x 512 floats (e1 then e2)
    float* sScr0= (float*)(smem + 40960);          // 144
    float* sScr1= (float*)(smem + 41536);          // 144
    float* v2i  = (float*)(smem + 42112);          // 64
    float* v2j  = (float*)(smem + 42368);          // 64
    float* v1i  = (float*)(smem + 42624);          // 9 (pad 16)
    float* v1j  = (float*)(smem + 42688);          // 9 (pad 16)
    float* colp = (float*)(smem + 42752);          // [2][8]
    float* sC   = (float*)(smem + 42816);          // 2 x 128 f32 (+s*128)
    float* sEmb = (float*)(smem + 43840);          // 1024 f32 (shared)
    u32*   W2F  = (u32*)(smem + 47936);            // 512 frags x 16B = 8192B

    const float* Cb0 = C + (2*blk)*128;
    const float* Cb1 = C + (2*blk+1)*128;

    // ================= P0 (8 waves, disjoint roles) =================
    if (wv == 0) {
        if (lane >= 32 && lane < 41) {            // v1i[f] = W1[f][:] . a1_i
            int f = lane - 32; float a0 = 0.f, a1 = 0.f;
            for (int q = 0; q < 16; q += 2) {
                float4 w = *(const float4*)(W1 + f*64 + q*4);
                float4 x = *(const float4*)(A1 + q*4);
                a0 += w.x*x.x + w.y*x.y + w.z*x.z + w.w*x.w;
                float4 w2 = *(const float4*)(W1 + f*64 + (q+1)*4);
                float4 x2 = *(const float4*)(A1 + (q+1)*4);
                a1 += w2.x*x2.x + w2.y*x2.y + w2.z*x2.z + w2.w*x2.w;
            }
            v1i[f] = a0 + a1;
        } else if (lane >= 48 && lane < 57) {     // v1j
            int f = lane - 48; float a0 = 0.f, a1 = 0.f;
            for (int q = 0; q < 16; q += 2) {
                float4 w = *(const float4*)(W1 + f*64 + q*4);
                float4 x = *(const float4*)(A1 + 64 + q*4);
                a0 += w.x*x.x + w.y*x.y + w.z*x.z + w.w*x.w;
                float4 w2 = *(const float4*)(W1 + f*64 + (q+1)*4);
                float4 x2 = *(const float4*)(A1 + 64 + (q+1)*4);
                a1 += w2.x*x2.x + w2.y*x2.y + w2.z*x2.z + w2.w*x2.w;
            }
            v1j[f] = a0 + a1;
        }
    } else if (wv == 3) {                         // v2i/v2j + W2 fragment pre-pack
        float ai0 = 0.f, ai1 = 0.f, aj0 = 0.f, aj1 = 0.f;
        for (int q = 0; q < 16; ++q) {
            float4 w  = *(const float4*)(W2 + lane*64 + q*4);
            float4 xi = *(const float4*)(A2 + q*4);
            float4 xj = *(const float4*)(A2 + 64 + q*4);
            ai0 += w.x*xi.x + w.y*xi.y; ai1 += w.z*xi.z + w.w*xi.w;
            aj0 += w.x*xj.x + w.y*xj.y; aj1 += w.z*xj.z + w.w*xj.w;
        }
        v2i[lane] = ai0 + ai1; v2j[lane] = aj0 + aj1;
        // W2F pack: coalesced row pairs -> fragment words
        const int ctp = lane >> 4, l15p = lane & 15;
        #pragma unroll
        for (int r = 0; r < 64; r += 2) {
            const int ks = r >> 5, q4g = (r >> 3) & 3, m = (r & 7) >> 1;
            const u32 val = cvtpk(W2[r*64 + lane], W2[(r+1)*64 + lane]);
            W2F[(((ks*4 + ctp)*4 + q4g)*16 + l15p)*4 + m] = val;
        }
    } else if (wv == 1 || wv == 4) {              // q_mlp heads (wave-private)
        const float* Cb = (wv == 1) ? Cb0 : Cb1;
        float* sScr = (wv == 1) ? sScr0 : sScr1;
        float a0 = 0.f, a1 = 0.f, a2v = 0.f, a3 = 0.f;
        for (int k = 0; k < 128; k += 4) {
            float4 c4 = *(const float4*)(Cb + k);
            a0  += c4.x*MLP1W[k*64+lane];
            a1  += c4.y*MLP1W[(k+1)*64+lane];
            a2v += c4.z*MLP1W[(k+2)*64+lane];
            a3  += c4.w*MLP1W[(k+3)*64+lane];
        }
        sScr[lane] = fmaxf(a0+a1+a2v+a3 + MLP1B[lane], 0.f);
        float b0 = 0.f, b1 = 0.f, b2 = 0.f, b3 = 0.f;
        for (int k = 0; k < 64; k += 4) {
            b0 += sScr[k]  *MLP2W[k*64 + lane];
            b1 += sScr[k+1]*MLP2W[(k+1)*64 + lane];
            b2 += sScr[k+2]*MLP2W[(k+2)*64 + lane];
            b3 += sScr[k+3]*MLP2W[(k+3)*64 + lane];
        }
        float x2 = fmaxf(b0+b1+b2+b3 + MLP2B[lane], 0.f);
        float p1 = x2 * HMW[lane];
        #pragma unroll
        for (int off = 32; off >= 1; off >>= 1) p1 += __shfl_down(p1, off);
        if (lane == 0) sScr[128] = p1 + HMB[0];
    } else if (wv == 2 || wv == 5) {              // gate heads (wave-private)
        const float* Cb = (wv == 2) ? Cb0 : Cb1;
        float* sScr = (wv == 2) ? sScr0 : sScr1;
        float a0 = 0.f, a1 = 0.f, a2v = 0.f, a3 = 0.f;
        for (int k = 0; k < 128; k += 4) {
            float4 c4 = *(const float4*)(Cb + k);
            a0  += c4.x*G1W[k*64+lane];
            a1  += c4.y*G1W[(k+1)*64+lane];
            a2v += c4.z*G1W[(k+2)*64+lane];
            a3  += c4.w*G1W[(k+3)*64+lane];
        }
        float g1 = fmaxf(a0+a1+a2v+a3 + G1B[lane], 0.f);
        float p2 = g1 * G2W[lane];
        #pragma unroll
        for (int off = 32; off >= 1; off >>= 1) p2 += __shfl_down(p2, off);
        if (lane == 0) sScr[129] = 1.f / (1.f + __expf(-(p2 + G2B[0])));
    } else if (wv == 6) {                         // stage EMB -> LDS (shared)
        #pragma unroll
        for (int q = 0; q < 4; ++q)
            ((float4*)sEmb)[lane + 64*q] = ((const float4*)EMB)[lane + 64*q];
    } else {                                      // wv==7: stage C rows (both)
        if (lane < 32)       ((float4*)sC)[lane] = ((const float4*)Cb0)[lane];
        else                 ((float4*)(sC+128))[lane-32] = ((const float4*)Cb1)[lane-32];
    }
    __syncthreads();   // b1

    // ========== P1: Wh1T for both elements (w1f shared) + e1 exps ==========
    {
        const int o = lane, cc = wv;
        float w1f[9];
        #pragma unroll
        for (int f = 0; f < 9; ++f) w1f[f] = W1[f*64 + o];
        #pragma unroll
        for (int s = 0; s < 2; ++s) {
            const float* cs = sC + s*128;
            float whv[16];
            #pragma unroll
            for (int i = 0; i < 16; ++i) {
                const int ig = cc*16 + i;
                float a = cs[ig] * w1f[0];
                float4 e0 = *(const float4*)(sEmb + ig*8);
                float4 e1 = *(const float4*)(sEmb + ig*8 + 4);
                a += e0.x*w1f[1] + e0.y*w1f[2] + e0.z*w1f[3] + e0.w*w1f[4];
                a += e1.x*w1f[5] + e1.y*w1f[6] + e1.z*w1f[7] + e1.w*w1f[8];
                whv[i] = a;
            }
            u32 p[8];
            #pragma unroll
            for (int q = 0; q < 8; ++q) p[q] = cvtpk(whv[2*q], whv[2*q+1]);
            uint4* dst = (uint4*)(R1 + s*9216 + o*136 + cc*16);
            dst[0] = ((uint4*)p)[0]; dst[1] = ((uint4*)p)[1];
        }
    }
    if (t < 256) {
        const int s = t >> 7, row = t & 127;
        const float* cs = sC + s*128;
        float c = cs[row];
        float4 e0 = *(const float4*)(sEmb + row*8);
        float4 e1 = *(const float4*)(sEmb + row*8 + 4);
        float ei = c*v1i[0] + e0.x*v1i[1]+e0.y*v1i[2]+e0.z*v1i[3]+e0.w*v1i[4]
                            + e1.x*v1i[5]+e1.y*v1i[6]+e1.z*v1i[7]+e1.w*v1i[8];
        float ej = c*v1j[0] + e0.x*v1j[1]+e0.y*v1j[2]+e0.z*v1j[3]+e0.w*v1j[4]
                            + e1.x*v1j[5]+e1.y*v1j[6]+e1.z*v1j[7]+e1.w*v1j[8];
        float* eb = expb + s*512;
        eb[row]       = __expf(ei); eb[128 + row] = __expf(0.2f*ei);
        eb[256 + row] = __expf(ej); eb[384 + row] = __expf(0.2f*ej);
    }
    __syncthreads();   // b2

    // h1 kept ONLY in registers (packed bf16): used by P6 (via shuffles) + P7 residual.
    uint2 h1p[2][4];

    // ==== P4: flash1 x2; b3; epilogue: LN1 -> h1p regs, e2 exps, fused P6 ====
    {
        v4f acc[2][4]; v4f accD[2];
        flash_att2(wv, l15, q4, adjr, expb, R1, acc, accD);
        __syncthreads();   // b3: all flash1 reads of R1(Wh1T) and expb(e1) done

        float4 g4[4], b4[4], vi4[4], vj4[4];
        #pragma unroll
        for (int ct = 0; ct < 4; ++ct) {
            g4[ct] = *(const float4*)(LN1G + 16*ct + 4*q4);
            b4[ct] = *(const float4*)(LN1B + 16*ct + 4*q4);
            vi4[ct] = *(const float4*)(v2i + 16*ct + 4*q4);
            vj4[ct] = *(const float4*)(v2j + 16*ct + 4*q4);
        }
        const int row = 16*wv + l15;
        #pragma unroll
        for (int s = 0; s < 2; ++s) {
            const float rd = 1.f / accD[s][0];
            float x[4][4]; float s1 = 0.f, s2 = 0.f;
            #pragma unroll
            for (int ct = 0; ct < 4; ++ct) {
                #pragma unroll
                for (int reg = 0; reg < 4; ++reg) {
                    float v = acc[s][ct][reg] * rd;
                    v = (v > 0.f) ? v : (__expf(v) - 1.f);      // ELU
                    x[ct][reg] = v;
                }
                s1 += (x[ct][0]+x[ct][1]) + (x[ct][2]+x[ct][3]);
                s2 += (x[ct][0]*x[ct][0]+x[ct][1]*x[ct][1])
                    + (x[ct][2]*x[ct][2]+x[ct][3]*x[ct][3]);
            }
            s1 += __shfl_xor(s1, 16); s2 += __shfl_xor(s2, 16);
            s1 += __shfl_xor(s1, 32); s2 += __shfl_xor(s2, 32);
            const float mean = s1 * (1.f/64.f);
            const float var  = s2 * (1.f/64.f) - mean*mean;
            const float rstd = rsqrtf(var + 1e-5f);
            float ei = 0.f, ej = 0.f;
            #pragma unroll
            for (int ct = 0; ct < 4; ++ct) {
                float h0 = (x[ct][0] - mean) * rstd * g4[ct].x + b4[ct].x;
                float h1 = (x[ct][1] - mean) * rstd * g4[ct].y + b4[ct].y;
                float h2 = (x[ct][2] - mean) * rstd * g4[ct].z + b4[ct].z;
                float h3 = (x[ct][3] - mean) * rstd * g4[ct].w + b4[ct].w;
                uint2 pw; pw.x = cvtpk(h0, h1); pw.y = cvtpk(h2, h3);
                h1p[s][ct] = pw;
                ei += h0*vi4[ct].x + h1*vi4[ct].y + h2*vi4[ct].z + h3*vi4[ct].w;
                ej += h0*vj4[ct].x + h1*vj4[ct].y + h2*vj4[ct].z + h3*vj4[ct].w;
            }
            ei += __shfl_xor(ei, 16); ei += __shfl_xor(ei, 32);
            ej += __shfl_xor(ej, 16); ej += __shfl_xor(ej, 32);
            if (q4 == 0) {    // e2 exps (e1 values dead after b3)
                float* eb = expb + s*512;
                eb[row]       = __expf(ei); eb[128 + row] = __expf(0.2f*ei);
                eb[256 + row] = __expf(ej); eb[384 + row] = __expf(0.2f*ej);
            }
        }

        // ---- fused P6: Wh2 = h1@W2; A-frags from h1p shuffles, B-frags from W2F ----
        v4f acc2[2][4];
        #pragma unroll
        for (int s = 0; s < 2; ++s)
            #pragma unroll
            for (int ct = 0; ct < 4; ++ct) acc2[s][ct] = (v4f){0.f,0.f,0.f,0.f};
        const int srcA = l15 + 16*((2*q4)     & 3);
        const int srcB = l15 + 16*((2*q4 + 1) & 3);
        const bool hi  = (q4 >> 1) & 1;
        #pragma unroll
        for (int ks = 0; ks < 2; ++ks) {
            v8s Af[2];
            #pragma unroll
            for (int s = 0; s < 2; ++s) {
                const u32 lo_x = h1p[s][2*ks  ].x, lo_y = h1p[s][2*ks  ].y;
                const u32 hi_x = h1p[s][2*ks+1].x, hi_y = h1p[s][2*ks+1].y;
                u32 a0x = (u32)__shfl((int)lo_x, srcA);
                u32 a1x = (u32)__shfl((int)hi_x, srcA);
                u32 a0y = (u32)__shfl((int)lo_y, srcA);
                u32 a1y = (u32)__shfl((int)hi_y, srcA);
                u32 b0x = (u32)__shfl((int)lo_x, srcB);
                u32 b1x = (u32)__shfl((int)hi_x, srcB);
                u32 b0y = (u32)__shfl((int)lo_y, srcB);
                u32 b1y = (u32)__shfl((int)hi_y, srcB);
                union { uint4 u; v8s v; } c;
                c.u.x = hi ? a1x : a0x;   // cols kb+0,kb+1
                c.u.y = hi ? a1y : a0y;   // cols kb+2,kb+3
                c.u.z = hi ? b1x : b0x;   // cols kb+4,kb+5
                c.u.w = hi ? b1y : b0y;   // cols kb+6,kb+7
                Af[s] = c.v;
            }
            #pragma unroll
            for (int ct = 0; ct < 4; ++ct) {
                v8s Bf = *(const v8s*)(W2F + (((ks*4 + ct)*4 + q4)*16 + l15)*4);
                acc2[0][ct] = __builtin_amdgcn_mfma_f32_16x16x32_bf16(Af[0], Bf, acc2[0][ct], 0,0,0);
                acc2[1][ct] = __builtin_amdgcn_mfma_f32_16x16x32_bf16(Af[1], Bf, acc2[1][ct], 0,0,0);
            }
        }
        // write Wh2T into R1 (safe: all Wh1T reads finished at b3)
        const int rb = 16*wv + 4*q4;
        #pragma unroll
        for (int s = 0; s < 2; ++s) {
            u16* wt = R1 + s*9216;
            #pragma unroll
            for (int ct = 0; ct < 4; ++ct) {
                const int col = 16*ct + l15;
                uint2 p;
                p.x = cvtpk(acc2[s][ct][0], acc2[s][ct][1]);
                p.y = cvtpk(acc2[s][ct][2], acc2[s][ct][3]);
                *(uint2*)(wt + col*136 + rb) = p;
            }
        }
    }
    __syncthreads();   // b6: Wh2T + e2 exps ready

    // ===== P7: flash2 x2 + (1/D, +h1 relu, LN2, head dot) =====
    {
        v4f acc[2][4]; v4f accD[2];
        flash_att2(wv, l15, q4, adjr, expb, R1, acc, accD);

        float4 g4[4], b4[4], hg4[4];
        #pragma unroll
        for (int ct = 0; ct < 4; ++ct) {
            g4[ct] = *(const float4*)(LN2G + 16*ct + 4*q4);
            b4[ct] = *(const float4*)(LN2B + 16*ct + 4*q4);
            hg4[ct] = *(const float4*)(HGW + 16*ct + 4*q4);
        }
        #pragma unroll
        for (int s = 0; s < 2; ++s) {
            const float rd = 1.f / accD[s][0];
            float x[4][4]; float s1 = 0.f, s2 = 0.f;
            #pragma unroll
            for (int ct = 0; ct < 4; ++ct) {
                const uint2 pw = h1p[s][ct];
                const float hv[4] = {bflo(pw.x), bfhi(pw.x), bflo(pw.y), bfhi(pw.y)};
                #pragma unroll
                for (int reg = 0; reg < 4; ++reg)
                    x[ct][reg] = fmaxf(acc[s][ct][reg] * rd + hv[reg], 0.f);
                s1 += (x[ct][0]+x[ct][1]) + (x[ct][2]+x[ct][3]);
                s2 += (x[ct][0]*x[ct][0]+x[ct][1]*x[ct][1])
                    + (x[ct][2]*x[ct][2]+x[ct][3]*x[ct][3]);
            }
            s1 += __shfl_xor(s1, 16); s2 += __shfl_xor(s2, 16);
            s1 += __shfl_xor(s1, 32); s2 += __shfl_xor(s2, 32);
            const float mean = s1 * (1.f/64.f);
            const float var  = s2 * (1.f/64.f) - mean*mean;
            const float rstd = rsqrtf(var + 1e-5f);
            float ptot = 0.f;
            #pragma unroll
            for (int ct = 0; ct < 4; ++ct) {
                float y0 = (x[ct][0] - mean) * rstd * g4[ct].x + b4[ct].x;
                float y1 = (x[ct][1] - mean) * rstd * g4[ct].y + b4[ct].y;
                float y2 = (x[ct][2] - mean) * rstd * g4[ct].z + b4[ct].z;
                float y3 = (x[ct][3] - mean) * rstd * g4[ct].w + b4[ct].w;
                ptot += y0*hg4[ct].x + y1*hg4[ct].y + y2*hg4[ct].z + y3*hg4[ct].w;
            }
            ptot += __shfl_xor(ptot, 1);  ptot += __shfl_xor(ptot, 2);
            ptot += __shfl_xor(ptot, 4);  ptot += __shfl_xor(ptot, 8);
            ptot += __shfl_xor(ptot, 16); ptot += __shfl_xor(ptot, 32);
            if (lane == 0) colp[s*8 + wv] = ptot;
        }
    }
    __syncthreads();   // b8

    // ================= final combine (both outputs) =================
    if (t == 0) {
        float hgb = HGB[0];
        float s0 = ((colp[0] + colp[1]) + (colp[2] + colp[3]))
                 + ((colp[4] + colp[5]) + (colp[6] + colp[7]));
        OUT[2*blk]   = sScr0[128] + sScr0[129] * (s0 * (1.f/128.f) + hgb);
        float s1 = ((colp[8] + colp[9]) + (colp[10] + colp[11]))
                 + ((colp[12] + colp[13]) + (colp[14] + colp[15]));
        OUT[2*blk+1] = sScr1[128] + sScr1[129] * (s1 * (1.f/128.f) + hgb);
    }
}

extern "C" void kernel_launch(void* const* d_in, const int* in_sizes, int n_in,
                              void* d_out, int out_size, void* d_ws, size_t ws_size,
                              hipStream_t stream) {
    (void)n_in; (void)out_size; (void)d_ws; (void)ws_size;
    const float* C     = (const float*)d_in[0];
    const float* ADJ   = (const float*)d_in[1];
    const float* EMB   = (const float*)d_in[2];
    const float* W1    = (const float*)d_in[3];
    const float* A1    = (const float*)d_in[4];
    const float* W2    = (const float*)d_in[5];
    const float* A2    = (const float*)d_in[6];
    const float* LN1G  = (const float*)d_in[7];
    const float* LN1B  = (const float*)d_in[8];
    const float* LN2G  = (const float*)d_in[9];
    const float* LN2B  = (const float*)d_in[10];
    const float* HGW   = (const float*)d_in[11];
    const float* HGB   = (const float*)d_in[12];
    const float* MLP1W = (const float*)d_in[13];
    const float* MLP1B = (const float*)d_in[14];
    const float* MLP2W = (const float*)d_in[15];
    const float* MLP2B = (const float*)d_in[16];
    const float* HMW   = (const float*)d_in[17];
    const float* HMB   = (const float*)d_in[18];
    const float* G1W   = (const float*)d_in[19];
    const float* G1B   = (const float*)d_in[20];
    const float* G2W   = (const float*)d_in[21];
    const float* G2B   = (const float*)d_in[22];

    const int B = in_sizes[0] / 128;  // 1024

    graphmixer_kernel<<<dim3(B/2), dim3(512), 0, stream>>>(
        C, ADJ, EMB, W1, A1, W2, A2, LN1G, LN1B, LN2G, LN2B,
        HGW, HGB, MLP1W, MLP1B, MLP2W, MLP2B, HMW, HMB,
        G1W, G1B, G2W, G2B, (float*)d_out);
}

// Round 13
// 127.589 us; speedup vs baseline: 1.1301x; 1.1301x over previous
//
#include <hip/hip_runtime.h>
#include <hip/hip_bf16.h>

typedef unsigned short u16;
typedef unsigned int u32;
typedef short v8s __attribute__((ext_vector_type(8)));
typedef float v4f __attribute__((ext_vector_type(4)));

__device__ __forceinline__ float bflo(u32 d){union{u32 i;float f;}u;u.i=d<<16;return u.f;}
__device__ __forceinline__ float bfhi(u32 d){union{u32 i;float f;}u;u.i=d&0xffff0000u;return u.f;}
// Packed f32x2 -> bf16x2; compiler emits v_cvt_pk_bf16_f32 from this (m240).
__device__ __forceinline__ u32 cvtpk(float a, float b){
    __hip_bfloat162 h = __float22bfloat162_rn(make_float2(a, b));
    u32 r; __builtin_memcpy(&r, &h, sizeof(r)); return r;
}
__device__ __forceinline__ v8s pack8(const float* w){
    union { uint4 u; v8s v; } c;
    c.u.x = cvtpk(w[0],w[1]); c.u.y = cvtpk(w[2],w[3]);
    c.u.z = cvtpk(w[4],w[5]); c.u.w = cvtpk(w[6],w[7]);
    return c.v;
}

// Transposed flash for TWO batch elements at once (ILP): per wave, row strip
// r0 = 16wv+l15; element s in {0,1}. ADJ row loads are shared across s.
// expb layout (floats): s*512 + {0:Ei,128:Fi,256:Ej,384:Fj} + row.
// whtb: element s at +s*9216 u16, [col][136] bf16.
// acc[s][ct][reg] = O_s[r0][16ct+4q4+reg]; accD[s][*] = D_s[r0].
__device__ __forceinline__ void flash_att2(
    int wv, int l15, int q4,
    const float* __restrict__ ADJ,
    const float* __restrict__ expb,
    const u16* __restrict__ whtb,
    v4f acc[2][4], v4f accD[2])
{
    const int r0 = 16*wv + l15;
    const float Ei0 = expb[r0],       Fi0 = expb[128 + r0];
    const float Ei1 = expb[512 + r0], Fi1 = expb[640 + r0];
    const v8s ONES = {16256,16256,16256,16256,16256,16256,16256,16256}; // bf16 1.0
    #pragma unroll
    for (int s = 0; s < 2; ++s) {
        accD[s] = (v4f){0.f,0.f,0.f,0.f};
        #pragma unroll
        for (int ct = 0; ct < 4; ++ct) acc[s][ct] = (v4f){0.f,0.f,0.f,0.f};
    }

    for (int ks = 0; ks < 4; ++ks) {
        const int ko = ks*32 + q4*8;
        float w0[8], w1[8];
        #pragma unroll
        for (int half = 0; half < 2; ++half) {
            float4 E0 = *(const float4*)(expb + 256 + ko + 4*half);
            float4 F0 = *(const float4*)(expb + 384 + ko + 4*half);
            float4 E1 = *(const float4*)(expb + 768 + ko + 4*half);
            float4 F1 = *(const float4*)(expb + 896 + ko + 4*half);
            float4 a  = *(const float4*)(ADJ + r0*128 + ko + 4*half);   // shared
            float Ev0[4] = {E0.x,E0.y,E0.z,E0.w};
            float Fv0[4] = {F0.x,F0.y,F0.z,F0.w};
            float Ev1[4] = {E1.x,E1.y,E1.z,E1.w};
            float Fv1[4] = {F1.x,F1.y,F1.z,F1.w};
            float av[4]  = {a.x,a.y,a.z,a.w};
            #pragma unroll
            for (int k = 0; k < 4; ++k) {
                w0[half*4 + k] = fmaxf(Ei0*Ev0[k], Fi0*Fv0[k]) * av[k];
                w1[half*4 + k] = fmaxf(Ei1*Ev1[k], Fi1*Fv1[k]) * av[k];
            }
        }
        v8s A0 = pack8(w0), A1 = pack8(w1);
        accD[0] = __builtin_amdgcn_mfma_f32_16x16x32_bf16(ONES, A0, accD[0], 0,0,0);
        accD[1] = __builtin_amdgcn_mfma_f32_16x16x32_bf16(ONES, A1, accD[1], 0,0,0);
        #pragma unroll
        for (int ct = 0; ct < 4; ++ct) {
            v8s Wt0 = *(const v8s*)(whtb + (16*ct + l15)*136 + ko);
            v8s Wt1 = *(const v8s*)(whtb + 9216 + (16*ct + l15)*136 + ko);
            acc[0][ct] = __builtin_amdgcn_mfma_f32_16x16x32_bf16(Wt0, A0, acc[0][ct], 0,0,0);
            acc[1][ct] = __builtin_amdgcn_mfma_f32_16x16x32_bf16(Wt1, A1, acc[1][ct], 0,0,0);
        }
    }
}

// 512 threads (8 waves), TWO batch elements per block (grid 512 = 2 blocks/CU).
// h1 lives only in registers: P6's A-fragment (8 contiguous cols kb..kb+7 of own
// row) is rebuilt via cross-lane shuffles within the 4 q4-lanes of an l15 group:
//   owner of col c: lane q4_o=(c>>2)&3, slot ct_o=c>>4, reg c&3
//   for c=32ks+8q4+j: ct_o=2ks+(q4>>1); srcA=(2q4)&3 (j=0..3), srcB=(2q4+1)&3 (j=4..7)
// -> 5 barriers total; P6 fused into the LN1 epilogue.
// ADJ is read inside the flashes (staggered across blocks -> L2/L3 reuse; the
// r12 entry-preload variant regressed: synchronized cold storm, FETCH 8.8->22MB).
// launch_bounds (512,4): cap 128 VGPR; ",7" proved to force spills (r5/r7).
__global__ __launch_bounds__(512, 4) void graphmixer_kernel(
    const float* __restrict__ C,     // (1024,128)
    const float* __restrict__ ADJ,   // (128,128)
    const float* __restrict__ EMB,   // (128,8)
    const float* __restrict__ W1,    // (9,64)
    const float* __restrict__ A1,    // (128)
    const float* __restrict__ W2,    // (64,64)
    const float* __restrict__ A2,    // (128)
    const float* __restrict__ LN1G, const float* __restrict__ LN1B,
    const float* __restrict__ LN2G, const float* __restrict__ LN2B,
    const float* __restrict__ HGW,  const float* __restrict__ HGB,
    const float* __restrict__ MLP1W, const float* __restrict__ MLP1B,
    const float* __restrict__ MLP2W, const float* __restrict__ MLP2B,
    const float* __restrict__ HMW,  const float* __restrict__ HMB,
    const float* __restrict__ G1W,  const float* __restrict__ G1B,
    const float* __restrict__ G2W,  const float* __restrict__ G2B,
    float* __restrict__ OUT)
{
    const int blk = blockIdx.x, t = threadIdx.x;
    const int lane = t & 63, wv = t >> 6;   // wv 0..7
    const int l15 = lane & 15, q4 = lane >> 4;

    __shared__ __align__(16) unsigned char smem[47936];
    // R1_s: [64][136] bf16 Wh1T then Wh2T (time-muxed across b3).
    u16*   R1   = (u16*)(smem);                    // +s*18432 bytes (9216 u16)
    float* expb = (float*)(smem + 36864);          // 2 x 512 floats (e1 then e2)
    float* sScr0= (float*)(smem + 40960);          // 144
    float* sScr1= (float*)(smem + 41536);          // 144
    float* v2i  = (float*)(smem + 42112);          // 64
    float* v2j  = (float*)(smem + 42368);          // 64
    float* v1i  = (float*)(smem + 42624);          // 9 (pad 16)
    float* v1j  = (float*)(smem + 42688);          // 9 (pad 16)
    float* colp = (float*)(smem + 42752);          // [2][8]
    float* sC   = (float*)(smem + 42816);          // 2 x 128 f32 (+s*128)
    float* sEmb = (float*)(smem + 43840);          // 1024 f32 (shared)

    const float* Cb0 = C + (2*blk)*128;
    const float* Cb1 = C + (2*blk+1)*128;

    // ================= P0 (8 waves, disjoint roles) =================
    if (wv == 0) {
        if (lane >= 32 && lane < 41) {            // v1i[f] = W1[f][:] . a1_i
            int f = lane - 32; float a0 = 0.f, a1 = 0.f;
            for (int q = 0; q < 16; q += 2) {
                float4 w = *(const float4*)(W1 + f*64 + q*4);
                float4 x = *(const float4*)(A1 + q*4);
                a0 += w.x*x.x + w.y*x.y + w.z*x.z + w.w*x.w;
                float4 w2 = *(const float4*)(W1 + f*64 + (q+1)*4);
                float4 x2 = *(const float4*)(A1 + (q+1)*4);
                a1 += w2.x*x2.x + w2.y*x2.y + w2.z*x2.z + w2.w*x2.w;
            }
            v1i[f] = a0 + a1;
        } else if (lane >= 48 && lane < 57) {     // v1j
            int f = lane - 48; float a0 = 0.f, a1 = 0.f;
            for (int q = 0; q < 16; q += 2) {
                float4 w = *(const float4*)(W1 + f*64 + q*4);
                float4 x = *(const float4*)(A1 + 64 + q*4);
                a0 += w.x*x.x + w.y*x.y + w.z*x.z + w.w*x.w;
                float4 w2 = *(const float4*)(W1 + f*64 + (q+1)*4);
                float4 x2 = *(const float4*)(A1 + 64 + (q+1)*4);
                a1 += w2.x*x2.x + w2.y*x2.y + w2.z*x2.z + w2.w*x2.w;
            }
            v1j[f] = a0 + a1;
        }
    } else if (wv == 3) {                         // v2i/v2j[k] = W2[k][:] . a2_{i,j}
        float ai0 = 0.f, ai1 = 0.f, aj0 = 0.f, aj1 = 0.f;
        for (int q = 0; q < 16; ++q) {
            float4 w  = *(const float4*)(W2 + lane*64 + q*4);
            float4 xi = *(const float4*)(A2 + q*4);
            float4 xj = *(const float4*)(A2 + 64 + q*4);
            ai0 += w.x*xi.x + w.y*xi.y; ai1 += w.z*xi.z + w.w*xi.w;
            aj0 += w.x*xj.x + w.y*xj.y; aj1 += w.z*xj.z + w.w*xj.w;
        }
        v2i[lane] = ai0 + ai1; v2j[lane] = aj0 + aj1;
    } else if (wv == 1 || wv == 4) {              // q_mlp heads (wave-private)
        const float* Cb = (wv == 1) ? Cb0 : Cb1;
        float* sScr = (wv == 1) ? sScr0 : sScr1;
        float a0 = 0.f, a1 = 0.f, a2v = 0.f, a3 = 0.f;
        for (int k = 0; k < 128; k += 4) {
            float4 c4 = *(const float4*)(Cb + k);
            a0  += c4.x*MLP1W[k*64+lane];
            a1  += c4.y*MLP1W[(k+1)*64+lane];
            a2v += c4.z*MLP1W[(k+2)*64+lane];
            a3  += c4.w*MLP1W[(k+3)*64+lane];
        }
        sScr[lane] = fmaxf(a0+a1+a2v+a3 + MLP1B[lane], 0.f);
        float b0 = 0.f, b1 = 0.f, b2 = 0.f, b3 = 0.f;
        for (int k = 0; k < 64; k += 4) {
            b0 += sScr[k]  *MLP2W[k*64 + lane];
            b1 += sScr[k+1]*MLP2W[(k+1)*64 + lane];
            b2 += sScr[k+2]*MLP2W[(k+2)*64 + lane];
            b3 += sScr[k+3]*MLP2W[(k+3)*64 + lane];
        }
        float x2 = fmaxf(b0+b1+b2+b3 + MLP2B[lane], 0.f);
        float p1 = x2 * HMW[lane];
        #pragma unroll
        for (int off = 32; off >= 1; off >>= 1) p1 += __shfl_down(p1, off);
        if (lane == 0) sScr[128] = p1 + HMB[0];
    } else if (wv == 2 || wv == 5) {              // gate heads (wave-private)
        const float* Cb = (wv == 2) ? Cb0 : Cb1;
        float* sScr = (wv == 2) ? sScr0 : sScr1;
        float a0 = 0.f, a1 = 0.f, a2v = 0.f, a3 = 0.f;
        for (int k = 0; k < 128; k += 4) {
            float4 c4 = *(const float4*)(Cb + k);
            a0  += c4.x*G1W[k*64+lane];
            a1  += c4.y*G1W[(k+1)*64+lane];
            a2v += c4.z*G1W[(k+2)*64+lane];
            a3  += c4.w*G1W[(k+3)*64+lane];
        }
        float g1 = fmaxf(a0+a1+a2v+a3 + G1B[lane], 0.f);
        float p2 = g1 * G2W[lane];
        #pragma unroll
        for (int off = 32; off >= 1; off >>= 1) p2 += __shfl_down(p2, off);
        if (lane == 0) sScr[129] = 1.f / (1.f + __expf(-(p2 + G2B[0])));
    } else if (wv == 6) {                         // stage EMB -> LDS (shared)
        #pragma unroll
        for (int q = 0; q < 4; ++q)
            ((float4*)sEmb)[lane + 64*q] = ((const float4*)EMB)[lane + 64*q];
    } else {                                      // wv==7: stage C rows (both)
        if (lane < 32)       ((float4*)sC)[lane] = ((const float4*)Cb0)[lane];
        else                 ((float4*)(sC+128))[lane-32] = ((const float4*)Cb1)[lane-32];
    }
    __syncthreads();   // b1

    // ========== P1: Wh1T for both elements (w1f shared) + e1 exps ==========
    {
        const int o = lane, cc = wv;
        float w1f[9];
        #pragma unroll
        for (int f = 0; f < 9; ++f) w1f[f] = W1[f*64 + o];
        #pragma unroll
        for (int s = 0; s < 2; ++s) {
            const float* cs = sC + s*128;
            float whv[16];
            #pragma unroll
            for (int i = 0; i < 16; ++i) {
                const int ig = cc*16 + i;
                float a = cs[ig] * w1f[0];
                float4 e0 = *(const float4*)(sEmb + ig*8);
                float4 e1 = *(const float4*)(sEmb + ig*8 + 4);
                a += e0.x*w1f[1] + e0.y*w1f[2] + e0.z*w1f[3] + e0.w*w1f[4];
                a += e1.x*w1f[5] + e1.y*w1f[6] + e1.z*w1f[7] + e1.w*w1f[8];
                whv[i] = a;
            }
            u32 p[8];
            #pragma unroll
            for (int q = 0; q < 8; ++q) p[q] = cvtpk(whv[2*q], whv[2*q+1]);
            uint4* dst = (uint4*)(R1 + s*9216 + o*136 + cc*16);
            dst[0] = ((uint4*)p)[0]; dst[1] = ((uint4*)p)[1];
        }
    }
    if (t < 256) {
        const int s = t >> 7, row = t & 127;
        const float* cs = sC + s*128;
        float c = cs[row];
        float4 e0 = *(const float4*)(sEmb + row*8);
        float4 e1 = *(const float4*)(sEmb + row*8 + 4);
        float ei = c*v1i[0] + e0.x*v1i[1]+e0.y*v1i[2]+e0.z*v1i[3]+e0.w*v1i[4]
                            + e1.x*v1i[5]+e1.y*v1i[6]+e1.z*v1i[7]+e1.w*v1i[8];
        float ej = c*v1j[0] + e0.x*v1j[1]+e0.y*v1j[2]+e0.z*v1j[3]+e0.w*v1j[4]
                            + e1.x*v1j[5]+e1.y*v1j[6]+e1.z*v1j[7]+e1.w*v1j[8];
        float* eb = expb + s*512;
        eb[row]       = __expf(ei); eb[128 + row] = __expf(0.2f*ei);
        eb[256 + row] = __expf(ej); eb[384 + row] = __expf(0.2f*ej);
    }
    __syncthreads();   // b2

    // h1 kept ONLY in registers (packed bf16): used by P6 (via shuffles) + P7 residual.
    uint2 h1p[2][4];

    // ==== P4: flash1 x2; b3; epilogue: LN1 -> h1p regs, e2 exps, fused P6 ====
    {
        v4f acc[2][4]; v4f accD[2];
        flash_att2(wv, l15, q4, ADJ, expb, R1, acc, accD);
        __syncthreads();   // b3: all flash1 reads of R1(Wh1T) and expb(e1) done

        float4 g4[4], b4[4], vi4[4], vj4[4];
        #pragma unroll
        for (int ct = 0; ct < 4; ++ct) {
            g4[ct] = *(const float4*)(LN1G + 16*ct + 4*q4);
            b4[ct] = *(const float4*)(LN1B + 16*ct + 4*q4);
            vi4[ct] = *(const float4*)(v2i + 16*ct + 4*q4);
            vj4[ct] = *(const float4*)(v2j + 16*ct + 4*q4);
        }
        const int row = 16*wv + l15;
        #pragma unroll
        for (int s = 0; s < 2; ++s) {
            const float rd = 1.f / accD[s][0];
            float x[4][4]; float s1 = 0.f, s2 = 0.f;
            #pragma unroll
            for (int ct = 0; ct < 4; ++ct) {
                #pragma unroll
                for (int reg = 0; reg < 4; ++reg) {
                    float v = acc[s][ct][reg] * rd;
                    v = (v > 0.f) ? v : (__expf(v) - 1.f);      // ELU
                    x[ct][reg] = v;
                }
                s1 += (x[ct][0]+x[ct][1]) + (x[ct][2]+x[ct][3]);
                s2 += (x[ct][0]*x[ct][0]+x[ct][1]*x[ct][1])
                    + (x[ct][2]*x[ct][2]+x[ct][3]*x[ct][3]);
            }
            s1 += __shfl_xor(s1, 16); s2 += __shfl_xor(s2, 16);
            s1 += __shfl_xor(s1, 32); s2 += __shfl_xor(s2, 32);
            const float mean = s1 * (1.f/64.f);
            const float var  = s2 * (1.f/64.f) - mean*mean;
            const float rstd = rsqrtf(var + 1e-5f);
            float ei = 0.f, ej = 0.f;
            #pragma unroll
            for (int ct = 0; ct < 4; ++ct) {
                float h0 = (x[ct][0] - mean) * rstd * g4[ct].x + b4[ct].x;
                float h1 = (x[ct][1] - mean) * rstd * g4[ct].y + b4[ct].y;
                float h2 = (x[ct][2] - mean) * rstd * g4[ct].z + b4[ct].z;
                float h3 = (x[ct][3] - mean) * rstd * g4[ct].w + b4[ct].w;
                uint2 pw; pw.x = cvtpk(h0, h1); pw.y = cvtpk(h2, h3);
                h1p[s][ct] = pw;
                ei += h0*vi4[ct].x + h1*vi4[ct].y + h2*vi4[ct].z + h3*vi4[ct].w;
                ej += h0*vj4[ct].x + h1*vj4[ct].y + h2*vj4[ct].z + h3*vj4[ct].w;
            }
            ei += __shfl_xor(ei, 16); ei += __shfl_xor(ei, 32);
            ej += __shfl_xor(ej, 16); ej += __shfl_xor(ej, 32);
            if (q4 == 0) {    // e2 exps (e1 values dead after b3)
                float* eb = expb + s*512;
                eb[row]       = __expf(ei); eb[128 + row] = __expf(0.2f*ei);
                eb[256 + row] = __expf(ej); eb[384 + row] = __expf(0.2f*ej);
            }
        }

        // ---- fused P6: Wh2 = h1@W2, A-frags from h1p via shuffles ----
        v4f acc2[2][4];
        #pragma unroll
        for (int s = 0; s < 2; ++s)
            #pragma unroll
            for (int ct = 0; ct < 4; ++ct) acc2[s][ct] = (v4f){0.f,0.f,0.f,0.f};
        const int srcA = l15 + 16*((2*q4)     & 3);
        const int srcB = l15 + 16*((2*q4 + 1) & 3);
        const bool hi  = (q4 >> 1) & 1;
        #pragma unroll
        for (int ks = 0; ks < 2; ++ks) {
            const int kb = ks*32 + q4*8;
            v8s Af[2];
            #pragma unroll
            for (int s = 0; s < 2; ++s) {
                const u32 lo_x = h1p[s][2*ks  ].x, lo_y = h1p[s][2*ks  ].y;
                const u32 hi_x = h1p[s][2*ks+1].x, hi_y = h1p[s][2*ks+1].y;
                u32 a0x = (u32)__shfl((int)lo_x, srcA);
                u32 a1x = (u32)__shfl((int)hi_x, srcA);
                u32 a0y = (u32)__shfl((int)lo_y, srcA);
                u32 a1y = (u32)__shfl((int)hi_y, srcA);
                u32 b0x = (u32)__shfl((int)lo_x, srcB);
                u32 b1x = (u32)__shfl((int)hi_x, srcB);
                u32 b0y = (u32)__shfl((int)lo_y, srcB);
                u32 b1y = (u32)__shfl((int)hi_y, srcB);
                union { uint4 u; v8s v; } c;
                c.u.x = hi ? a1x : a0x;   // cols kb+0,kb+1
                c.u.y = hi ? a1y : a0y;   // cols kb+2,kb+3
                c.u.z = hi ? b1x : b0x;   // cols kb+4,kb+5
                c.u.w = hi ? b1y : b0y;   // cols kb+6,kb+7
                Af[s] = c.v;
            }
            #pragma unroll
            for (int ct = 0; ct < 4; ++ct) {
                const float* wp = W2 + kb*64 + 16*ct + l15;
                float w8[8];
                #pragma unroll
                for (int j = 0; j < 8; ++j) w8[j] = wp[j*64];
                v8s Bf = pack8(w8);                         // shared across s
                acc2[0][ct] = __builtin_amdgcn_mfma_f32_16x16x32_bf16(Af[0], Bf, acc2[0][ct], 0,0,0);
                acc2[1][ct] = __builtin_amdgcn_mfma_f32_16x16x32_bf16(Af[1], Bf, acc2[1][ct], 0,0,0);
            }
        }
        // write Wh2T into R1 (safe: all Wh1T reads finished at b3)
        const int rb = 16*wv + 4*q4;
        #pragma unroll
        for (int s = 0; s < 2; ++s) {
            u16* wt = R1 + s*9216;
            #pragma unroll
            for (int ct = 0; ct < 4; ++ct) {
                const int col = 16*ct + l15;
                uint2 p;
                p.x = cvtpk(acc2[s][ct][0], acc2[s][ct][1]);
                p.y = cvtpk(acc2[s][ct][2], acc2[s][ct][3]);
                *(uint2*)(wt + col*136 + rb) = p;
            }
        }
    }
    __syncthreads();   // b6: Wh2T + e2 exps ready

    // ===== P7: flash2 x2 + (1/D, +h1 relu, LN2, head dot) =====
    {
        v4f acc[2][4]; v4f accD[2];
        flash_att2(wv, l15, q4, ADJ, expb, R1, acc, accD);

        float4 g4[4], b4[4], hg4[4];
        #pragma unroll
        for (int ct = 0; ct < 4; ++ct) {
            g4[ct] = *(const float4*)(LN2G + 16*ct + 4*q4);
            b4[ct] = *(const float4*)(LN2B + 16*ct + 4*q4);
            hg4[ct] = *(const float4*)(HGW + 16*ct + 4*q4);
        }
        #pragma unroll
        for (int s = 0; s < 2; ++s) {
            const float rd = 1.f / accD[s][0];
            float x[4][4]; float s1 = 0.f, s2 = 0.f;
            #pragma unroll
            for (int ct = 0; ct < 4; ++ct) {
                const uint2 pw = h1p[s][ct];
                const float hv[4] = {bflo(pw.x), bfhi(pw.x), bflo(pw.y), bfhi(pw.y)};
                #pragma unroll
                for (int reg = 0; reg < 4; ++reg)
                    x[ct][reg] = fmaxf(acc[s][ct][reg] * rd + hv[reg], 0.f);
                s1 += (x[ct][0]+x[ct][1]) + (x[ct][2]+x[ct][3]);
                s2 += (x[ct][0]*x[ct][0]+x[ct][1]*x[ct][1])
                    + (x[ct][2]*x[ct][2]+x[ct][3]*x[ct][3]);
            }
            s1 += __shfl_xor(s1, 16); s2 += __shfl_xor(s2, 16);
            s1 += __shfl_xor(s1, 32); s2 += __shfl_xor(s2, 32);
            const float mean = s1 * (1.f/64.f);
            const float var  = s2 * (1.f/64.f) - mean*mean;
            const float rstd = rsqrtf(var + 1e-5f);
            float ptot = 0.f;
            #pragma unroll
            for (int ct = 0; ct < 4; ++ct) {
                float y0 = (x[ct][0] - mean) * rstd * g4[ct].x + b4[ct].x;
                float y1 = (x[ct][1] - mean) * rstd * g4[ct].y + b4[ct].y;
                float y2 = (x[ct][2] - mean) * rstd * g4[ct].z + b4[ct].z;
                float y3 = (x[ct][3] - mean) * rstd * g4[ct].w + b4[ct].w;
                ptot += y0*hg4[ct].x + y1*hg4[ct].y + y2*hg4[ct].z + y3*hg4[ct].w;
            }
            ptot += __shfl_xor(ptot, 1);  ptot += __shfl_xor(ptot, 2);
            ptot += __shfl_xor(ptot, 4);  ptot += __shfl_xor(ptot, 8);
            ptot += __shfl_xor(ptot, 16); ptot += __shfl_xor(ptot, 32);
            if (lane == 0) colp[s*8 + wv] = ptot;
        }
    }
    __syncthreads();   // b8

    // ================= final combine (both outputs) =================
    if (t == 0) {
        float hgb = HGB[0];
        float s0 = ((colp[0] + colp[1]) + (colp[2] + colp[3]))
                 + ((colp[4] + colp[5]) + (colp[6] + colp[7]));
        OUT[2*blk]   = sScr0[128] + sScr0[129] * (s0 * (1.f/128.f) + hgb);
        float s1 = ((colp[8] + colp[9]) + (colp[10] + colp[11]))
                 + ((colp[12] + colp[13]) + (colp[14] + colp[15]));
        OUT[2*blk+1] = sScr1[128] + sScr1[129] * (s1 * (1.f/128.f) + hgb);
    }
}

extern "C" void kernel_launch(void* const* d_in, const int* in_sizes, int n_in,
                              void* d_out, int out_size, void* d_ws, size_t ws_size,
                              hipStream_t stream) {
    (void)n_in; (void)out_size; (void)d_ws; (void)ws_size;
    const float* C     = (const float*)d_in[0];
    const float* ADJ   = (const float*)d_in[1];
    const float* EMB   = (const float*)d_in[2];
    const float* W1    = (const float*)d_in[3];
    const float* A1    = (const float*)d_in[4];
    const float* W2    = (const float*)d_in[5];
    const float* A2    = (const float*)d_in[6];
    const float* LN1G  = (const float*)d_in[7];
    const float* LN1B  = (const float*)d_in[8];
    const float* LN2G  = (const float*)d_in[9];
    const float* LN2B  = (const float*)d_in[10];
    const float* HGW   = (const float*)d_in[11];
    const float* HGB   = (const float*)d_in[12];
    const float* MLP1W = (const float*)d_in[13];
    const float* MLP1B = (const float*)d_in[14];
    const float* MLP2W = (const float*)d_in[15];
    const float* MLP2B = (const float*)d_in[16];
    const float* HMW   = (const float*)d_in[17];
    const float* HMB   = (const float*)d_in[18];
    const float* G1W   = (const float*)d_in[19];
    const float* G1B   = (const float*)d_in[20];
    const float* G2W   = (const float*)d_in[21];
    const float* G2B   = (const float*)d_in[22];

    const int B = in_sizes[0] / 128;  // 1024

    graphmixer_kernel<<<dim3(B/2), dim3(512), 0, stream>>>(
        C, ADJ, EMB, W1, A1, W2, A2, LN1G, LN1B, LN2G, LN2B,
        HGW, HGB, MLP1W, MLP1B, MLP2W, MLP2B, HMW, HMB,
        G1W, G1B, G2W, G2B, (float*)d_out);
}